// Round 1
// baseline (162.438 us; speedup 1.0000x reference)
//
#include <hip/hip_runtime.h>
#include <math.h>

#define HD 4096
#define ED 4096
#define LD 2048

// ---------------- reduction helpers (blockDim == 256) ----------------
__device__ __forceinline__ float wave_sum(float v) {
#pragma unroll
    for (int off = 32; off > 0; off >>= 1) v += __shfl_down(v, off, 64);
    return v;
}

__device__ __forceinline__ float block_sum256(float v, float* sm) {
    v = wave_sum(v);
    if ((threadIdx.x & 63) == 0) sm[threadIdx.x >> 6] = v;
    __syncthreads();
    float r = sm[0] + sm[1] + sm[2] + sm[3];
    __syncthreads();
    return r;
}

__device__ __forceinline__ float block_max256(float v, float* sm) {
#pragma unroll
    for (int off = 32; off > 0; off >>= 1) v = fmaxf(v, __shfl_down(v, off, 64));
    if ((threadIdx.x & 63) == 0) sm[threadIdx.x >> 6] = v;
    __syncthreads();
    float r = fmaxf(fmaxf(sm[0], sm[1]), fmaxf(sm[2], sm[3]));
    __syncthreads();
    return r;
}

// ---------------- GEMV over concat(x1=emb[token], x2) ; row len 8192 ----------------
__global__ __launch_bounds__(256) void gemv_cat8192(
    const float* __restrict__ W, const float* __restrict__ bias,
    const float* __restrict__ emb, const int* __restrict__ token,
    const float* __restrict__ x2, float* __restrict__ out, int do_relu)
{
    const int row = blockIdx.x;
    const int t = threadIdx.x;
    const float* x1 = emb + (size_t)token[0] * ED;
    const float4* Wr = reinterpret_cast<const float4*>(W + (size_t)row * 8192);
    const float4* X1 = reinterpret_cast<const float4*>(x1);
    const float4* X2 = reinterpret_cast<const float4*>(x2);
    float acc = 0.f;
#pragma unroll
    for (int i = 0; i < 4; ++i) {
        int idx = i * 256 + t;
        float4 w = Wr[idx];
        float4 x = X1[idx];
        acc = fmaf(w.x, x.x, acc); acc = fmaf(w.y, x.y, acc);
        acc = fmaf(w.z, x.z, acc); acc = fmaf(w.w, x.w, acc);
    }
#pragma unroll
    for (int i = 4; i < 8; ++i) {
        int idx = i * 256 + t;
        float4 w = Wr[idx];
        float4 x = X2[idx - 1024];
        acc = fmaf(w.x, x.x, acc); acc = fmaf(w.y, x.y, acc);
        acc = fmaf(w.z, x.z, acc); acc = fmaf(w.w, x.w, acc);
    }
    __shared__ float sm[4];
    acc = wave_sum(acc);
    if ((t & 63) == 0) sm[t >> 6] = acc;
    __syncthreads();
    if (t == 0) {
        float s = sm[0] + sm[1] + sm[2] + sm[3] + bias[row];
        out[row] = do_relu ? fmaxf(s, 0.f) : s;
    }
}

// ---------------- softmax over 2048 logits, writes ws copy + d_out copy ----------------
__global__ __launch_bounds__(256) void softmax2048(
    const float* __restrict__ logits, float* __restrict__ w, float* __restrict__ w2)
{
    __shared__ float sm[4];
    const int t = threadIdx.x;
    float vals[8];
    float m = -INFINITY;
#pragma unroll
    for (int i = 0; i < 8; ++i) { vals[i] = logits[i * 256 + t]; m = fmaxf(m, vals[i]); }
    m = block_max256(m, sm);
    float s = 0.f;
#pragma unroll
    for (int i = 0; i < 8; ++i) { vals[i] = expf(vals[i] - m); s += vals[i]; }
    s = block_sum256(s, sm);
    float inv = 1.f / s;
#pragma unroll
    for (int i = 0; i < 8; ++i) {
        float r = vals[i] * inv;
        w[i * 256 + t] = r;
        w2[i * 256 + t] = r;
    }
}

// ---------------- ctx = attn_w @ enc : partial over 32-row chunks ----------------
// grid (64, 4): blockIdx.x = row-chunk (32 rows), blockIdx.y = col-chunk (1024 cols)
__global__ __launch_bounds__(256) void ctx_partial(
    const float* __restrict__ enc, const float* __restrict__ w,
    float* __restrict__ partial /* [64][4096] */)
{
    const int rc = blockIdx.x;
    const int col4 = blockIdx.y * 256 + threadIdx.x;   // float4 index into 4096 cols
    float4 acc = make_float4(0.f, 0.f, 0.f, 0.f);
    const int r0 = rc * 32;
#pragma unroll 4
    for (int r = r0; r < r0 + 32; ++r) {
        float wv = w[r];
        float4 e = reinterpret_cast<const float4*>(enc + (size_t)r * HD)[col4];
        acc.x = fmaf(wv, e.x, acc.x); acc.y = fmaf(wv, e.y, acc.y);
        acc.z = fmaf(wv, e.z, acc.z); acc.w = fmaf(wv, e.w, acc.w);
    }
    reinterpret_cast<float4*>(partial + (size_t)rc * HD)[col4] = acc;
}

__global__ __launch_bounds__(256) void ctx_reduce(
    const float* __restrict__ partial, float* __restrict__ ctx)
{
    const int j = blockIdx.x * 256 + threadIdx.x;   // 4096 threads
    float s = 0.f;
#pragma unroll 8
    for (int k = 0; k < 64; ++k) s += partial[(size_t)k * HD + j];
    ctx[j] = s;
}

// ---------------- gates[r] = W_ih[r]·x + W_hh[r]·h + b_ih[r] + b_hh[r] ----------------
__global__ __launch_bounds__(256) void gemv_gates(
    const float* __restrict__ Wih, const float* __restrict__ Whh,
    const float* __restrict__ bih, const float* __restrict__ bhh,
    const float* __restrict__ x, const float* __restrict__ h,
    float* __restrict__ gates)
{
    const int row = blockIdx.x;
    const int t = threadIdx.x;
    const float4* Wi = reinterpret_cast<const float4*>(Wih + (size_t)row * HD);
    const float4* Wh = reinterpret_cast<const float4*>(Whh + (size_t)row * HD);
    const float4* X = reinterpret_cast<const float4*>(x);
    const float4* Hv = reinterpret_cast<const float4*>(h);
    float acc = 0.f;
#pragma unroll
    for (int i = 0; i < 4; ++i) {
        int idx = i * 256 + t;
        float4 w = Wi[idx];
        float4 xv = X[idx];
        acc = fmaf(w.x, xv.x, acc); acc = fmaf(w.y, xv.y, acc);
        acc = fmaf(w.z, xv.z, acc); acc = fmaf(w.w, xv.w, acc);
        float4 w2 = Wh[idx];
        float4 hv = Hv[idx];
        acc = fmaf(w2.x, hv.x, acc); acc = fmaf(w2.y, hv.y, acc);
        acc = fmaf(w2.z, hv.z, acc); acc = fmaf(w2.w, hv.w, acc);
    }
    __shared__ float sm[4];
    acc = wave_sum(acc);
    if ((t & 63) == 0) sm[t >> 6] = acc;
    __syncthreads();
    if (t == 0) gates[row] = sm[0] + sm[1] + sm[2] + sm[3] + bih[row] + bhh[row];
}

// ---------------- LSTM cell elementwise (4096) ----------------
__global__ __launch_bounds__(256) void lstm_cell(
    const float* __restrict__ gates, const float* __restrict__ c,
    float* __restrict__ hnew, float* __restrict__ out)
{
    const int j = blockIdx.x * 256 + threadIdx.x;
    float ig = gates[j];
    float fg = gates[j + HD];
    float gg = gates[j + 2 * HD];
    float og = gates[j + 3 * HD];
    float si = 1.f / (1.f + expf(-ig));
    float sf = 1.f / (1.f + expf(-fg));
    float so = 1.f / (1.f + expf(-og));
    float cn = sf * c[j] + si * tanhf(gg);
    float hn = so * tanhf(cn);
    hnew[j] = hn;
    out[HD + j] = hn;        // h_new
    out[2 * HD + j] = cn;    // c_new
}

// ---------------- out GEMV: 4096 rows, row len 4096 ----------------
__global__ __launch_bounds__(256) void gemv4096(
    const float* __restrict__ W, const float* __restrict__ bias,
    const float* __restrict__ x, float* __restrict__ out)
{
    const int row = blockIdx.x;
    const int t = threadIdx.x;
    const float4* Wr = reinterpret_cast<const float4*>(W + (size_t)row * HD);
    const float4* X = reinterpret_cast<const float4*>(x);
    float acc = 0.f;
#pragma unroll
    for (int i = 0; i < 4; ++i) {
        int idx = i * 256 + t;
        float4 w = Wr[idx];
        float4 xv = X[idx];
        acc = fmaf(w.x, xv.x, acc); acc = fmaf(w.y, xv.y, acc);
        acc = fmaf(w.z, xv.z, acc); acc = fmaf(w.w, xv.w, acc);
    }
    __shared__ float sm[4];
    acc = wave_sum(acc);
    if ((t & 63) == 0) sm[t >> 6] = acc;
    __syncthreads();
    if (t == 0) out[row] = sm[0] + sm[1] + sm[2] + sm[3] + bias[row];
}

// ---------------- log_softmax over 4096 ----------------
__global__ __launch_bounds__(256) void logsoftmax4096(
    const float* __restrict__ logits, float* __restrict__ out)
{
    __shared__ float sm[4];
    const int t = threadIdx.x;
    float vals[16];
    float m = -INFINITY;
#pragma unroll
    for (int i = 0; i < 16; ++i) { vals[i] = logits[i * 256 + t]; m = fmaxf(m, vals[i]); }
    m = block_max256(m, sm);
    float s = 0.f;
#pragma unroll
    for (int i = 0; i < 16; ++i) s += expf(vals[i] - m);
    s = block_sum256(s, sm);
    float lse = m + logf(s);
#pragma unroll
    for (int i = 0; i < 16; ++i) out[i * 256 + t] = vals[i] - lse;
}

extern "C" void kernel_launch(void* const* d_in, const int* in_sizes, int n_in,
                              void* d_out, int out_size, void* d_ws, size_t ws_size,
                              hipStream_t stream)
{
    const int*   token  = (const int*)  d_in[0];
    const float* h      = (const float*)d_in[1];
    const float* c      = (const float*)d_in[2];
    const float* enc    = (const float*)d_in[3];
    const float* emb    = (const float*)d_in[4];
    const float* W_attn = (const float*)d_in[5];
    const float* b_attn = (const float*)d_in[6];
    const float* W_comb = (const float*)d_in[7];
    const float* b_comb = (const float*)d_in[8];
    const float* W_ih   = (const float*)d_in[9];
    const float* W_hh   = (const float*)d_in[10];
    const float* b_ih   = (const float*)d_in[11];
    const float* b_hh   = (const float*)d_in[12];
    const float* W_out  = (const float*)d_in[13];
    const float* b_out  = (const float*)d_in[14];
    float* out = (float*)d_out;  // [logp 4096 | h_new 4096 | c_new 4096 | attn_w 2048]

    // ws layout (floats)
    float* ws          = (float*)d_ws;
    float* attn_logits = ws;             // 2048
    float* attn_w      = ws + 2048;      // 2048
    float* ctx         = ws + 4096;      // 4096
    float* hnew        = ws + 8192;      // 4096
    float* xvec        = ws + 12288;     // 4096
    float* gates       = ws + 16384;     // 16384
    float* logits      = ws + 32768;     // 4096
    float* partial     = ws + 36864;     // 64*4096

    // 1) attention logits: (2048 x 8192) @ cat(e, h)
    gemv_cat8192<<<LD, 256, 0, stream>>>(W_attn, b_attn, emb, token, h, attn_logits, 0);
    // 2) softmax -> attn_w (ws + d_out tail)
    softmax2048<<<1, 256, 0, stream>>>(attn_logits, attn_w, out + 3 * HD);
    // 3) ctx = attn_w @ encoder_outputs (deterministic two-pass)
    ctx_partial<<<dim3(64, 4), 256, 0, stream>>>(enc, attn_w, partial);
    ctx_reduce<<<16, 256, 0, stream>>>(partial, ctx);
    // 4) x = relu((4096 x 8192) @ cat(e, ctx) + b)
    gemv_cat8192<<<HD, 256, 0, stream>>>(W_comb, b_comb, emb, token, ctx, xvec, 1);
    // 5) gates = W_ih @ x + W_hh @ h + b_ih + b_hh
    gemv_gates<<<4 * HD, 256, 0, stream>>>(W_ih, W_hh, b_ih, b_hh, xvec, h, gates);
    // 6) LSTM cell -> h_new, c_new
    lstm_cell<<<16, 256, 0, stream>>>(gates, c, hnew, out);
    // 7) logits = W_out @ h_new + b_out
    gemv4096<<<HD, 256, 0, stream>>>(W_out, b_out, hnew, logits);
    // 8) log_softmax -> logp
    logsoftmax4096<<<1, 256, 0, stream>>>(logits, out);
}

// Round 2
// 156.222 us; speedup vs baseline: 1.0398x; 1.0398x over previous
//
#include <hip/hip_runtime.h>
#include <math.h>

#define HD 4096
#define LD 2048

// ---------------- reduction helpers ----------------
__device__ __forceinline__ float wave_sum(float v) {
#pragma unroll
    for (int off = 32; off > 0; off >>= 1) v += __shfl_down(v, off, 64);
    return v;
}
__device__ __forceinline__ float wave_max(float v) {
#pragma unroll
    for (int off = 32; off > 0; off >>= 1) v = fmaxf(v, __shfl_down(v, off, 64));
    return v;
}

// blockDim 256 variants (4 waves)
__device__ __forceinline__ float block_sum256(float v, float* sm) {
    v = wave_sum(v);
    if ((threadIdx.x & 63) == 0) sm[threadIdx.x >> 6] = v;
    __syncthreads();
    float r = sm[0] + sm[1] + sm[2] + sm[3];
    __syncthreads();
    return r;
}
__device__ __forceinline__ float block_max256(float v, float* sm) {
    v = wave_max(v);
    if ((threadIdx.x & 63) == 0) sm[threadIdx.x >> 6] = v;
    __syncthreads();
    float r = fmaxf(fmaxf(sm[0], sm[1]), fmaxf(sm[2], sm[3]));
    __syncthreads();
    return r;
}

// ---------------- K1: gates_hh (16384 rows) + attn logits (2048 rows) ----------------
// blocks [0,16384): gates_hh[r] = W_hh[r]·h + b_ih[r] + b_hh[r]
// blocks [16384,18432): attn_logits[r] = W_attn[r]·cat(e,h) + b_attn[r]
__global__ __launch_bounds__(256) void k1_hh_attn(
    const float* __restrict__ Whh, const float* __restrict__ bih,
    const float* __restrict__ bhh,
    const float* __restrict__ Wattn, const float* __restrict__ battn,
    const float* __restrict__ emb, const int* __restrict__ token,
    const float* __restrict__ h,
    float* __restrict__ gates_hh, float* __restrict__ attn_logits)
{
    const int t = threadIdx.x;
    const int bx = blockIdx.x;
    __shared__ float sm[4];
    if (bx < 4 * HD) {
        const float4* Wr = reinterpret_cast<const float4*>(Whh + (size_t)bx * HD);
        const float4* Hv = reinterpret_cast<const float4*>(h);
        float a0 = 0.f, a1 = 0.f;
#pragma unroll
        for (int i = 0; i < 4; i += 2) {
            int idx = i * 256 + t;
            float4 w = Wr[idx], x = Hv[idx];
            a0 = fmaf(w.x, x.x, a0); a0 = fmaf(w.y, x.y, a0);
            a0 = fmaf(w.z, x.z, a0); a0 = fmaf(w.w, x.w, a0);
            int idx2 = idx + 256;
            float4 w2 = Wr[idx2], x2 = Hv[idx2];
            a1 = fmaf(w2.x, x2.x, a1); a1 = fmaf(w2.y, x2.y, a1);
            a1 = fmaf(w2.z, x2.z, a1); a1 = fmaf(w2.w, x2.w, a1);
        }
        float acc = wave_sum(a0 + a1);
        if ((t & 63) == 0) sm[t >> 6] = acc;
        __syncthreads();
        if (t == 0) gates_hh[bx] = sm[0] + sm[1] + sm[2] + sm[3] + bih[bx] + bhh[bx];
    } else {
        const int row = bx - 4 * HD;
        const float* x1 = emb + (size_t)token[0] * HD;
        const float4* Wr = reinterpret_cast<const float4*>(Wattn + (size_t)row * 8192);
        const float4* X1 = reinterpret_cast<const float4*>(x1);
        const float4* X2 = reinterpret_cast<const float4*>(h);
        float a0 = 0.f, a1 = 0.f;
#pragma unroll
        for (int i = 0; i < 4; ++i) {
            int idx = i * 256 + t;
            float4 w = Wr[idx], x = X1[idx];
            a0 = fmaf(w.x, x.x, a0); a0 = fmaf(w.y, x.y, a0);
            a0 = fmaf(w.z, x.z, a0); a0 = fmaf(w.w, x.w, a0);
            int idx2 = idx + 1024;
            float4 w2 = Wr[idx2], x2 = X2[idx];
            a1 = fmaf(w2.x, x2.x, a1); a1 = fmaf(w2.y, x2.y, a1);
            a1 = fmaf(w2.z, x2.z, a1); a1 = fmaf(w2.w, x2.w, a1);
        }
        float acc = wave_sum(a0 + a1);
        if ((t & 63) == 0) sm[t >> 6] = acc;
        __syncthreads();
        if (t == 0) attn_logits[row] = sm[0] + sm[1] + sm[2] + sm[3] + battn[row];
    }
}

// ---------------- K2: fused softmax (redundant per block) + ctx partial ----------------
// grid (64,4): bx = 32-row chunk, by = 1024-col chunk. block (0,0) writes attn_w to d_out.
__global__ __launch_bounds__(256) void k2_softmax_ctx(
    const float* __restrict__ logits, const float* __restrict__ enc,
    float* __restrict__ partial /* [64][4096] */, float* __restrict__ attn_out)
{
    __shared__ float sm[4];
    __shared__ float smw[32];
    const int t = threadIdx.x;
    float vals[8];
    float m = -INFINITY;
#pragma unroll
    for (int i = 0; i < 8; ++i) { vals[i] = logits[i * 256 + t]; m = fmaxf(m, vals[i]); }
    m = block_max256(m, sm);
    float s = 0.f;
#pragma unroll
    for (int i = 0; i < 8; ++i) { vals[i] = expf(vals[i] - m); s += vals[i]; }
    s = block_sum256(s, sm);
    const float inv = 1.f / s;

    const int rc = blockIdx.x;
    const int r0 = rc * 32;
    // rows r0..r0+31 live in vals[r0>>8] of threads (r0&255)..(r0&255)+31
    const int tbase = r0 & 255;
    if (t >= tbase && t < tbase + 32) smw[t - tbase] = vals[r0 >> 8] * inv;
    if (rc == 0 && blockIdx.y == 0) {
#pragma unroll
        for (int i = 0; i < 8; ++i) attn_out[i * 256 + t] = vals[i] * inv;
    }
    __syncthreads();

    const int col4 = blockIdx.y * 256 + t;
    float4 acc = make_float4(0.f, 0.f, 0.f, 0.f);
#pragma unroll 4
    for (int r = 0; r < 32; ++r) {
        float wv = smw[r];
        float4 e = reinterpret_cast<const float4*>(enc + (size_t)(r0 + r) * HD)[col4];
        acc.x = fmaf(wv, e.x, acc.x); acc.y = fmaf(wv, e.y, acc.y);
        acc.z = fmaf(wv, e.z, acc.z); acc.w = fmaf(wv, e.w, acc.w);
    }
    reinterpret_cast<float4*>(partial + (size_t)rc * HD)[col4] = acc;
}

// ---------------- K3: ctx = column-sum of partial ----------------
__global__ __launch_bounds__(1024) void k3_ctx_reduce(
    const float* __restrict__ partial, float* __restrict__ ctx)
{
    const int j = blockIdx.x * 1024 + threadIdx.x;   // 4 blocks
    float s = 0.f;
#pragma unroll 8
    for (int k = 0; k < 64; ++k) s += partial[(size_t)k * HD + j];
    ctx[j] = s;
}

// ---------------- K4: x = relu(W_comb · cat(e, ctx) + b_comb) ----------------
__global__ __launch_bounds__(256) void k4_comb(
    const float* __restrict__ W, const float* __restrict__ bias,
    const float* __restrict__ emb, const int* __restrict__ token,
    const float* __restrict__ ctx, float* __restrict__ out)
{
    const int row = blockIdx.x;
    const int t = threadIdx.x;
    const float* x1 = emb + (size_t)token[0] * HD;
    const float4* Wr = reinterpret_cast<const float4*>(W + (size_t)row * 8192);
    const float4* X1 = reinterpret_cast<const float4*>(x1);
    const float4* X2 = reinterpret_cast<const float4*>(ctx);
    float a0 = 0.f, a1 = 0.f;
#pragma unroll
    for (int i = 0; i < 4; ++i) {
        int idx = i * 256 + t;
        float4 w = Wr[idx], x = X1[idx];
        a0 = fmaf(w.x, x.x, a0); a0 = fmaf(w.y, x.y, a0);
        a0 = fmaf(w.z, x.z, a0); a0 = fmaf(w.w, x.w, a0);
        int idx2 = idx + 1024;
        float4 w2 = Wr[idx2], x2 = X2[idx];
        a1 = fmaf(w2.x, x2.x, a1); a1 = fmaf(w2.y, x2.y, a1);
        a1 = fmaf(w2.z, x2.z, a1); a1 = fmaf(w2.w, x2.w, a1);
    }
    __shared__ float sm[4];
    float acc = wave_sum(a0 + a1);
    if ((t & 63) == 0) sm[t >> 6] = acc;
    __syncthreads();
    if (t == 0) out[row] = fmaxf(sm[0] + sm[1] + sm[2] + sm[3] + bias[row], 0.f);
}

// ---------------- K5: gates_ih (4 rows per block) + LSTM cell fused ----------------
__global__ __launch_bounds__(256) void k5_ih_cell(
    const float* __restrict__ Wih, const float* __restrict__ ghh,
    const float* __restrict__ x, const float* __restrict__ c,
    float* __restrict__ out /* d_out base */)
{
    const int j = blockIdx.x;   // cell index 0..4095
    const int t = threadIdx.x;
    const float4* X = reinterpret_cast<const float4*>(x);
    float acc[4] = {0.f, 0.f, 0.f, 0.f};
#pragma unroll
    for (int g = 0; g < 4; ++g) {
        const float4* Wr = reinterpret_cast<const float4*>(Wih + (size_t)(g * HD + j) * HD);
#pragma unroll
        for (int i = 0; i < 4; ++i) {
            int idx = i * 256 + t;
            float4 w = Wr[idx], xv = X[idx];
            acc[g] = fmaf(w.x, xv.x, acc[g]); acc[g] = fmaf(w.y, xv.y, acc[g]);
            acc[g] = fmaf(w.z, xv.z, acc[g]); acc[g] = fmaf(w.w, xv.w, acc[g]);
        }
    }
    __shared__ float sm[4][4];
#pragma unroll
    for (int g = 0; g < 4; ++g) {
        float v = wave_sum(acc[g]);
        if ((t & 63) == 0) sm[t >> 6][g] = v;
    }
    __syncthreads();
    if (t == 0) {
        float gi = sm[0][0] + sm[1][0] + sm[2][0] + sm[3][0] + ghh[j];
        float gf = sm[0][1] + sm[1][1] + sm[2][1] + sm[3][1] + ghh[HD + j];
        float gg = sm[0][2] + sm[1][2] + sm[2][2] + sm[3][2] + ghh[2 * HD + j];
        float go = sm[0][3] + sm[1][3] + sm[2][3] + sm[3][3] + ghh[3 * HD + j];
        float si = 1.f / (1.f + expf(-gi));
        float sf = 1.f / (1.f + expf(-gf));
        float so = 1.f / (1.f + expf(-go));
        float cn = sf * c[j] + si * tanhf(gg);
        float hn = so * tanhf(cn);
        out[HD + j] = hn;       // h_new
        out[2 * HD + j] = cn;   // c_new
    }
}

// ---------------- K6: logits = W_out · h_new + b_out ----------------
__global__ __launch_bounds__(256) void k6_out(
    const float* __restrict__ W, const float* __restrict__ bias,
    const float* __restrict__ x, float* __restrict__ out)
{
    const int row = blockIdx.x;
    const int t = threadIdx.x;
    const float4* Wr = reinterpret_cast<const float4*>(W + (size_t)row * HD);
    const float4* X = reinterpret_cast<const float4*>(x);
    float a0 = 0.f, a1 = 0.f;
#pragma unroll
    for (int i = 0; i < 4; i += 2) {
        int idx = i * 256 + t;
        float4 w = Wr[idx], xv = X[idx];
        a0 = fmaf(w.x, xv.x, a0); a0 = fmaf(w.y, xv.y, a0);
        a0 = fmaf(w.z, xv.z, a0); a0 = fmaf(w.w, xv.w, a0);
        int idx2 = idx + 256;
        float4 w2 = Wr[idx2], xv2 = X[idx2];
        a1 = fmaf(w2.x, xv2.x, a1); a1 = fmaf(w2.y, xv2.y, a1);
        a1 = fmaf(w2.z, xv2.z, a1); a1 = fmaf(w2.w, xv2.w, a1);
    }
    __shared__ float sm[4];
    float acc = wave_sum(a0 + a1);
    if ((t & 63) == 0) sm[t >> 6] = acc;
    __syncthreads();
    if (t == 0) out[row] = sm[0] + sm[1] + sm[2] + sm[3] + bias[row];
}

// ---------------- K7: log_softmax over 4096 (1024 threads) ----------------
__global__ __launch_bounds__(1024) void k7_logsoftmax(
    const float* __restrict__ logits, float* __restrict__ out)
{
    __shared__ float sm[16];
    const int t = threadIdx.x;
    float vals[4];
    float m = -INFINITY;
#pragma unroll
    for (int i = 0; i < 4; ++i) { vals[i] = logits[i * 1024 + t]; m = fmaxf(m, vals[i]); }
    m = wave_max(m);
    if ((t & 63) == 0) sm[t >> 6] = m;
    __syncthreads();
    float mm = -INFINITY;
#pragma unroll
    for (int k = 0; k < 16; ++k) mm = fmaxf(mm, sm[k]);
    __syncthreads();
    float s = 0.f;
#pragma unroll
    for (int i = 0; i < 4; ++i) s += expf(vals[i] - mm);
    s = wave_sum(s);
    if ((t & 63) == 0) sm[t >> 6] = s;
    __syncthreads();
    float ss = 0.f;
#pragma unroll
    for (int k = 0; k < 16; ++k) ss += sm[k];
    float lse = mm + logf(ss);
#pragma unroll
    for (int i = 0; i < 4; ++i) out[i * 1024 + t] = vals[i] - lse;
}

extern "C" void kernel_launch(void* const* d_in, const int* in_sizes, int n_in,
                              void* d_out, int out_size, void* d_ws, size_t ws_size,
                              hipStream_t stream)
{
    const int*   token  = (const int*)  d_in[0];
    const float* h      = (const float*)d_in[1];
    const float* c      = (const float*)d_in[2];
    const float* enc    = (const float*)d_in[3];
    const float* emb    = (const float*)d_in[4];
    const float* W_attn = (const float*)d_in[5];
    const float* b_attn = (const float*)d_in[6];
    const float* W_comb = (const float*)d_in[7];
    const float* b_comb = (const float*)d_in[8];
    const float* W_ih   = (const float*)d_in[9];
    const float* W_hh   = (const float*)d_in[10];
    const float* b_ih   = (const float*)d_in[11];
    const float* b_hh   = (const float*)d_in[12];
    const float* W_out  = (const float*)d_in[13];
    const float* b_out  = (const float*)d_in[14];
    float* out = (float*)d_out;  // [logp 4096 | h_new 4096 | c_new 4096 | attn_w 2048]

    // ws layout (floats)
    float* ws          = (float*)d_ws;
    float* attn_logits = ws;               // 2048
    float* ghh         = ws + 2048;        // 16384
    float* partial     = ws + 18432;       // 64*4096 = 262144
    float* ctx         = ws + 280576;      // 4096
    float* xvec        = ws + 284672;      // 4096
    float* logits      = ws + 288768;      // 4096

    // K1: gates_hh + attn logits (320 MB)
    k1_hh_attn<<<4 * HD + LD, 256, 0, stream>>>(
        W_hh, b_ih, b_hh, W_attn, b_attn, emb, token, h, ghh, attn_logits);
    // K2: softmax (redundant per block) + ctx partial; writes attn_w to d_out
    k2_softmax_ctx<<<dim3(64, 4), 256, 0, stream>>>(attn_logits, enc, partial, out + 3 * HD);
    // K3: ctx reduce
    k3_ctx_reduce<<<4, 1024, 0, stream>>>(partial, ctx);
    // K4: x = relu(W_comb @ cat(e, ctx) + b) (134 MB)
    k4_comb<<<HD, 256, 0, stream>>>(W_comb, b_comb, emb, token, ctx, xvec);
    // K5: gates_ih + LSTM cell fused (256 MB); writes h_new/c_new to d_out
    k5_ih_cell<<<HD, 256, 0, stream>>>(W_ih, ghh, xvec, c, out);
    // K6: logits = W_out @ h_new (67 MB)
    k6_out<<<HD, 256, 0, stream>>>(W_out, b_out, out + HD, logits);
    // K7: log_softmax -> logp
    k7_logsoftmax<<<1, 1024, 0, stream>>>(logits, out);
}